// Round 1
// baseline (2525.435 us; speedup 1.0000x reference)
//
#include <hip/hip_runtime.h>
#include <cstdint>
#include <cstddef>

#define N_NODES 100000
#define N_EDGES 1000000
#define N_GRAPHS 512
#define HID 64
#define EDIM 32
#define LAYERS 4
#define BN_EPS 1e-5

// ---------------- workspace layout (bytes) ----------------
static const size_t X_OFF    = 0;                                   // x: N*64 f32
static const size_t AGG_OFF  = (size_t)N_NODES * HID * 4;           // agg: N*64 f32
static const size_t STA_OFF  = AGG_OFF + (size_t)N_NODES * HID * 4; // statsA: 128 f64
static const size_t STB_OFF  = STA_OFF + 128 * 8;                   // statsB: 128 f64
static const size_t POOL_OFF = STB_OFF + 128 * 8;                   // pooled: 512*64 f32
static const size_t CNT_OFF  = POOL_OFF + (size_t)N_GRAPHS * HID * 4; // counts: 512 f32
static const size_t P_OFF    = CNT_OFF + (size_t)N_GRAPHS * 4;      // P: N*256 f32
// total ~153.7 MB

__device__ __forceinline__ float rl_f(float v, int k) {
    return __uint_as_float(__builtin_amdgcn_readlane(__float_as_uint(v), k));
}
__device__ __forceinline__ float sigmoidf_(float x) {
    return 1.f / (1.f + __expf(-x));
}
__device__ __forceinline__ float softplusf_(float x) {
    // stable: max(x,0) + log1p(exp(-|x|))
    return fmaxf(x, 0.f) + __logf(1.f + __expf(-fabsf(x)));
}

// ---------------- x = emb[z] ----------------
__global__ __launch_bounds__(256) void cg_embed(const int* __restrict__ z,
                                                const float* __restrict__ emb,
                                                float* __restrict__ x) {
    int i = blockIdx.x * 256 + threadIdx.x;
    if (i < N_NODES * HID) {
        x[i] = emb[z[i >> 6] * HID + (i & 63)];
    }
}

// ---------------- P = x @ [Wf(0:64)|Ws(0:64)|Wf(64:128)|Ws(64:128)] ----------------
// block: 256 threads, 16 rows/block, 16 col-quads per row-group. grid = N/16 (exact)
__global__ __launch_bounds__(256) void cg_nodeP(const float* __restrict__ x,
                                                const float* __restrict__ Wf,
                                                const float* __restrict__ Ws,
                                                float* __restrict__ P) {
    __shared__ __align__(16) float xs[16][68];  // +4 pad: conflict-free broadcast
    const int j4 = (threadIdx.x & 15) * 4;
    const int r  = threadIdx.x >> 4;
    const int base = blockIdx.x * 16;

    // stage 16 rows of x
    {
        const float4 v = *(const float4*)(x + (size_t)(base + r) * HID + j4);
        *(float4*)(&xs[r][j4]) = v;
    }
    __syncthreads();

    float4 a0 = {0, 0, 0, 0}, a1 = {0, 0, 0, 0}, a2 = {0, 0, 0, 0}, a3 = {0, 0, 0, 0};
#pragma unroll 4
    for (int k = 0; k < 64; k++) {
        float xv = xs[r][k];
        float4 w0 = *(const float4*)(Wf + (size_t)k * HID + j4);
        float4 w1 = *(const float4*)(Ws + (size_t)k * HID + j4);
        float4 w2 = *(const float4*)(Wf + (size_t)(64 + k) * HID + j4);
        float4 w3 = *(const float4*)(Ws + (size_t)(64 + k) * HID + j4);
        a0.x = fmaf(xv, w0.x, a0.x); a0.y = fmaf(xv, w0.y, a0.y);
        a0.z = fmaf(xv, w0.z, a0.z); a0.w = fmaf(xv, w0.w, a0.w);
        a1.x = fmaf(xv, w1.x, a1.x); a1.y = fmaf(xv, w1.y, a1.y);
        a1.z = fmaf(xv, w1.z, a1.z); a1.w = fmaf(xv, w1.w, a1.w);
        a2.x = fmaf(xv, w2.x, a2.x); a2.y = fmaf(xv, w2.y, a2.y);
        a2.z = fmaf(xv, w2.z, a2.z); a2.w = fmaf(xv, w2.w, a2.w);
        a3.x = fmaf(xv, w3.x, a3.x); a3.y = fmaf(xv, w3.y, a3.y);
        a3.z = fmaf(xv, w3.z, a3.z); a3.w = fmaf(xv, w3.w, a3.w);
    }
    float* o = P + (size_t)(base + r) * 256;
    *(float4*)(o + 0   + j4) = a0;
    *(float4*)(o + 64  + j4) = a1;
    *(float4*)(o + 128 + j4) = a2;
    *(float4*)(o + 192 + j4) = a3;
}

// ---------------- edge kernel: gates + scatter-add ----------------
// wave = 1 edge per iteration; thread j in [0,64) owns output feature j.
__global__ __launch_bounds__(256) void cg_edge(const float* __restrict__ P,
                                               const int* __restrict__ ei,
                                               const float* __restrict__ ea,
                                               const float* __restrict__ WfE,
                                               const float* __restrict__ WsE,
                                               const float* __restrict__ bf,
                                               const float* __restrict__ bs,
                                               float* __restrict__ agg) {
    const int j = threadIdx.x & 63;
    float wfe[EDIM], wse[EDIM];
#pragma unroll
    for (int k = 0; k < EDIM; k++) {
        wfe[k] = WfE[k * HID + j];
        wse[k] = WsE[k * HID + j];
    }
    const float bfv = bf[j], bsv = bs[j];
    const int wave = blockIdx.x * 4 + (threadIdx.x >> 6);
    const int nwaves = gridDim.x * 4;

    // prefetch first edge's indices + attr
    int e = wave;
    int eu = __builtin_amdgcn_readfirstlane(e);
    int ps = ei[eu];
    int pd = ei[N_EDGES + eu];
    float per = ea[(size_t)eu * EDIM + (j & 31)];

    for (; e < N_EDGES; e += nwaves) {
        const int srcn = ps, dstn = pd;
        const float er = per;
        const int ne = e + nwaves;
        if (ne < N_EDGES) {
            const int neu = __builtin_amdgcn_readfirstlane(ne);
            ps = ei[neu];
            pd = ei[N_EDGES + neu];
            per = ea[(size_t)neu * EDIM + (j & 31)];
        }
        const size_t db = (size_t)dstn * 256, sb = (size_t)srcn * 256;
        const float pf0 = P[db + j];
        const float pf1 = P[sb + 128 + j];
        const float ps0 = P[db + 64 + j];
        const float ps1 = P[sb + 192 + j];
        float uf = bfv, us = bsv;
#pragma unroll
        for (int k = 0; k < EDIM; k++) {
            const float ek = rl_f(er, k);
            uf = fmaf(ek, wfe[k], uf);
            us = fmaf(ek, wse[k], us);
        }
        uf += pf0 + pf1;
        us += ps0 + ps1;
        const float m = sigmoidf_(uf) * softplusf_(us);
        unsafeAtomicAdd(&agg[(size_t)dstn * HID + j], m);
    }
}

// ---------------- column stats (sum, sumsq) of agg ----------------
__global__ __launch_bounds__(256) void cg_stats(const float* __restrict__ a,
                                                double* __restrict__ st) {
    const int j = threadIdx.x & 63, rl = threadIdx.x >> 6;
    float s = 0.f, q = 0.f;
    for (int n = blockIdx.x * 4 + rl; n < N_NODES; n += gridDim.x * 4) {
        float v = a[(size_t)n * HID + j];
        s += v;
        q += v * v;
    }
    __shared__ float ls[4][64], lq[4][64];
    ls[rl][j] = s;
    lq[rl][j] = q;
    __syncthreads();
    if (threadIdx.x < 64) {
        float S = ls[0][j] + ls[1][j] + ls[2][j] + ls[3][j];
        float Q = lq[0][j] + lq[1][j] + lq[2][j] + lq[3][j];
        unsafeAtomicAdd(&st[j], (double)S);
        unsafeAtomicAdd(&st[64 + j], (double)Q);
    }
}

// ---------------- y = BN1(agg)+x (in-place into agg) ; accumulate BN2 stats ----------------
__global__ __launch_bounds__(256) void cg_bn1res(float* __restrict__ agg,
                                                 const float* __restrict__ x,
                                                 const float* __restrict__ g,
                                                 const float* __restrict__ b,
                                                 const double* __restrict__ stA,
                                                 double* __restrict__ stB) {
    const int j = threadIdx.x & 63, rl = threadIdx.x >> 6;
    const double mean = stA[j] * (1.0 / N_NODES);
    const double var  = stA[64 + j] * (1.0 / N_NODES) - mean * mean;
    const float sc = (float)((double)g[j] / sqrt(var + BN_EPS));
    const float sh = (float)((double)b[j] - mean * (double)sc);
    float s = 0.f, q = 0.f;
    for (int n = blockIdx.x * 4 + rl; n < N_NODES; n += gridDim.x * 4) {
        size_t idx = (size_t)n * HID + j;
        float v = fmaf(agg[idx], sc, sh) + x[idx];
        agg[idx] = v;
        s += v;
        q += v * v;
    }
    __shared__ float ls[4][64], lq[4][64];
    ls[rl][j] = s;
    lq[rl][j] = q;
    __syncthreads();
    if (threadIdx.x < 64) {
        float S = ls[0][j] + ls[1][j] + ls[2][j] + ls[3][j];
        float Q = lq[0][j] + lq[1][j] + lq[2][j] + lq[3][j];
        unsafeAtomicAdd(&stB[j], (double)S);
        unsafeAtomicAdd(&stB[64 + j], (double)Q);
    }
}

// ---------------- x = softplus(BN2(y)) ----------------
__global__ __launch_bounds__(256) void cg_bn2act(const float* __restrict__ agg,
                                                 float* __restrict__ x,
                                                 const float* __restrict__ g,
                                                 const float* __restrict__ b,
                                                 const double* __restrict__ stB) {
    const int j = threadIdx.x & 63, rl = threadIdx.x >> 6;
    const double mean = stB[j] * (1.0 / N_NODES);
    const double var  = stB[64 + j] * (1.0 / N_NODES) - mean * mean;
    const float sc = (float)((double)g[j] / sqrt(var + BN_EPS));
    const float sh = (float)((double)b[j] - mean * (double)sc);
    for (int n = blockIdx.x * 4 + rl; n < N_NODES; n += gridDim.x * 4) {
        size_t idx = (size_t)n * HID + j;
        x[idx] = softplusf_(fmaf(agg[idx], sc, sh));
    }
}

// ---------------- segment-mean pool (sum + counts; sorted batch_ids → run flush) ----------------
__global__ __launch_bounds__(256) void cg_pool(const float* __restrict__ x,
                                               const int* __restrict__ bid,
                                               float* __restrict__ pooled,
                                               float* __restrict__ cnt) {
    const int j = threadIdx.x & 63, rl = threadIdx.x >> 6;
    const int chunk = (N_NODES + gridDim.x - 1) / gridDim.x;
    const int s0 = blockIdx.x * chunk;
    const int e0 = min(s0 + chunk, N_NODES);
    float acc = 0.f, c = 0.f;
    int cur = -1;
    for (int n = s0 + rl; n < e0; n += 4) {
        int bg = bid[n];
        if (bg != cur) {
            if (cur >= 0) {
                unsafeAtomicAdd(&pooled[(size_t)cur * HID + j], acc);
                if (j == 0) unsafeAtomicAdd(&cnt[cur], c);
            }
            cur = bg;
            acc = 0.f;
            c = 0.f;
        }
        acc += x[(size_t)n * HID + j];
        c += 1.f;
    }
    if (cur >= 0) {
        unsafeAtomicAdd(&pooled[(size_t)cur * HID + j], acc);
        if (j == 0) unsafeAtomicAdd(&cnt[cur], c);
    }
}

// ---------------- per-graph MLP head ----------------
__global__ __launch_bounds__(64) void cg_mlp(const float* __restrict__ pooled,
                                             const float* __restrict__ cnt,
                                             const float* __restrict__ W1,
                                             const float* __restrict__ b1,
                                             const float* __restrict__ W2,
                                             const float* __restrict__ b2,
                                             float* __restrict__ out) {
    const int g = blockIdx.x;
    const int j = threadIdx.x;
    const float c = fmaxf(cnt[g], 1.f);
    const float p = pooled[(size_t)g * HID + j] / c;
    float h = b1[j];
    for (int k = 0; k < HID; k++) {
        h = fmaf(rl_f(p, k), W1[k * HID + j], h);
    }
    const float hs = h * sigmoidf_(h);  // silu
    float v = hs * W2[j];
#pragma unroll
    for (int off = 32; off > 0; off >>= 1) v += __shfl_down(v, off);
    if (j == 0) out[g] = v + b2[0];
}

extern "C" void kernel_launch(void* const* d_in, const int* in_sizes, int n_in,
                              void* d_out, int out_size, void* d_ws, size_t ws_size,
                              hipStream_t stream) {
    const int*   z   = (const int*)d_in[0];
    const int*   ei  = (const int*)d_in[1];
    const float* ea  = (const float*)d_in[2];
    const int*   bid = (const int*)d_in[3];
    const float* emb = (const float*)d_in[4];
    const float* Wf  = (const float*)d_in[5];
    const float* bf  = (const float*)d_in[6];
    const float* Ws  = (const float*)d_in[7];
    const float* bs  = (const float*)d_in[8];
    const float* gc  = (const float*)d_in[9];
    const float* bc  = (const float*)d_in[10];
    const float* go  = (const float*)d_in[11];
    const float* bo  = (const float*)d_in[12];
    const float* W1  = (const float*)d_in[13];
    const float* b1  = (const float*)d_in[14];
    const float* W2  = (const float*)d_in[15];
    const float* b2  = (const float*)d_in[16];
    float* out = (float*)d_out;

    char* ws = (char*)d_ws;
    float*  x      = (float*)(ws + X_OFF);
    float*  agg    = (float*)(ws + AGG_OFF);
    double* stA    = (double*)(ws + STA_OFF);
    double* stB    = (double*)(ws + STB_OFF);
    float*  pooled = (float*)(ws + POOL_OFF);
    float*  cnt    = (float*)(ws + CNT_OFF);
    float*  P      = (float*)(ws + P_OFF);

    cg_embed<<<(N_NODES * HID + 255) / 256, 256, 0, stream>>>(z, emb, x);

    for (int l = 0; l < LAYERS; l++) {
        const float* Wfl = Wf + (size_t)l * 160 * HID;
        const float* Wsl = Ws + (size_t)l * 160 * HID;
        // zero agg + statsA + statsB (contiguous)
        hipMemsetAsync(ws + AGG_OFF, 0, (size_t)N_NODES * HID * 4 + 2048, stream);
        cg_nodeP<<<N_NODES / 16, 256, 0, stream>>>(x, Wfl, Wsl, P);
        cg_edge<<<4096, 256, 0, stream>>>(P, ei, ea, Wfl + 128 * HID, Wsl + 128 * HID,
                                          bf + l * HID, bs + l * HID, agg);
        cg_stats<<<1024, 256, 0, stream>>>(agg, stA);
        cg_bn1res<<<1024, 256, 0, stream>>>(agg, x, gc + l * HID, bc + l * HID, stA, stB);
        cg_bn2act<<<1024, 256, 0, stream>>>(agg, x, go + l * HID, bo + l * HID, stB);
    }

    hipMemsetAsync(ws + POOL_OFF, 0, (size_t)N_GRAPHS * HID * 4 + N_GRAPHS * 4, stream);
    cg_pool<<<1024, 256, 0, stream>>>(x, bid, pooled, cnt);
    cg_mlp<<<N_GRAPHS, 64, 0, stream>>>(pooled, cnt, W1, b1, W2, b2, out);
}

// Round 3
// 2492.697 us; speedup vs baseline: 1.0131x; 1.0131x over previous
//
#include <hip/hip_runtime.h>
#include <cstdint>
#include <cstddef>

#define N_NODES 100000
#define N_EDGES 1000000
#define N_GRAPHS 512
#define HID 64
#define EDIM 32
#define LAYERS 4
#define BN_EPS 1e-5

// ---------------- workspace layout (bytes, 256-aligned) ----------------
static const size_t X_OFF    = 0;                                   // x: N*64 f32 (25.6 MB)
static const size_t AGG_OFF  = X_OFF + 25600000;                    // agg: N*64 f32
static const size_t STA_OFF  = AGG_OFF + 25600000;                  // statsA: 128 f64
static const size_t STB_OFF  = STA_OFF + 1024;                      // statsB: 128 f64
static const size_t POOL_OFF = STB_OFF + 1024;                      // pooled: 512*64 f32
static const size_t CNT_OFF  = POOL_OFF + 131072;                   // counts: 512 f32
static const size_t DEG_OFF  = CNT_OFF + 2048;                      // deg: N int
static const size_t ECUR_OFF = DEG_OFF + 400128;                    // ecur: N int
static const size_t PERM_OFF = ECUR_OFF + 400128;                   // perm: E int (4 MB)
static const size_t DSTS_OFF = PERM_OFF + 4000000;                  // dst_sorted: E int (4 MB)
static const size_t P_OFF    = DSTS_OFF + 4000000;                  // P: N*256 f32 (102.4 MB)
// total ~162.5 MB

__device__ __forceinline__ float rl_f(float v, int k) {
    return __uint_as_float(__builtin_amdgcn_readlane(__float_as_uint(v), k));
}
__device__ __forceinline__ float sigmoidf_(float x) {
    return 1.f / (1.f + __expf(-x));
}
__device__ __forceinline__ float softplusf_(float x) {
    return fmaxf(x, 0.f) + __logf(1.f + __expf(-fabsf(x)));
}
__device__ __forceinline__ void fma4(float4& a, const float4& wv, float xv) {
    a.x = fmaf(xv, wv.x, a.x);
    a.y = fmaf(xv, wv.y, a.y);
    a.z = fmaf(xv, wv.z, a.z);
    a.w = fmaf(xv, wv.w, a.w);
}

// ---------------- x = emb[z] ----------------
__global__ __launch_bounds__(256) void cg_embed(const int* __restrict__ z,
                                                const float* __restrict__ emb,
                                                float* __restrict__ x) {
    int i = blockIdx.x * 256 + threadIdx.x;
    if (i < N_NODES * HID) {
        x[i] = emb[z[i >> 6] * HID + (i & 63)];
    }
}

// ---------------- counting sort by dst: histogram ----------------
__global__ __launch_bounds__(256) void cg_hist(const int* __restrict__ ei,
                                               int* __restrict__ deg) {
    int e = blockIdx.x * 256 + threadIdx.x;
    if (e < N_EDGES) atomicAdd(&deg[ei[N_EDGES + e]], 1);
}

// ---------------- exclusive scan of deg -> ecur (single block) ----------------
#define SPAN 98
__global__ __launch_bounds__(1024) void cg_scan(const int* __restrict__ deg,
                                                int* __restrict__ ecur) {
    __shared__ int ps[1024];
    const int t = threadIdx.x;
    const int s0 = t * SPAN;
    int sum = 0;
    for (int i = 0; i < SPAN; i++) {
        int idx = s0 + i;
        if (idx < N_NODES) sum += deg[idx];
    }
    ps[t] = sum;
    __syncthreads();
    for (int off = 1; off < 1024; off <<= 1) {
        int v = (t >= off) ? ps[t - off] : 0;
        __syncthreads();
        ps[t] += v;
        __syncthreads();
    }
    int run = ps[t] - sum;  // exclusive prefix of this thread's span
    for (int i = 0; i < SPAN; i++) {
        int idx = s0 + i;
        if (idx < N_NODES) {
            ecur[idx] = run;
            run += deg[idx];
        }
    }
}

// ---------------- scatter: perm[pos]=edge, dst_s[pos]=dst ----------------
__global__ __launch_bounds__(256) void cg_scatter(const int* __restrict__ ei,
                                                  int* __restrict__ ecur,
                                                  int* __restrict__ perm,
                                                  int* __restrict__ dst_s) {
    int e = blockIdx.x * 256 + threadIdx.x;
    if (e < N_EDGES) {
        int d = ei[N_EDGES + e];
        int pos = atomicAdd(&ecur[d], 1);
        perm[pos] = e;
        dst_s[pos] = d;
    }
}

// ---------------- P = x @ [Wf(0:64)|Ws(0:64)|Wf(64:128)|Ws(64:128)] ----------------
// 4-row register blocking: block=256, 64 rows/block, 64 acc VGPRs/thread.
__global__ __launch_bounds__(256) void cg_nodeP4(const float* __restrict__ x,
                                                 const float* __restrict__ Wf,
                                                 const float* __restrict__ Ws,
                                                 float* __restrict__ P) {
    __shared__ __align__(16) float xs[64][68];
    const int tid = threadIdx.x;
    const int base = blockIdx.x * 64;
#pragma unroll
    for (int i = 0; i < 4; i++) {
        int f4 = tid * 4 + i;           // 0..1023 over [64 rows][16 float4]
        int r = f4 >> 4, c4 = (f4 & 15) * 4;
        float4 v = {0, 0, 0, 0};
        if (base + r < N_NODES) v = *(const float4*)(x + (size_t)(base + r) * HID + c4);
        *(float4*)(&xs[r][c4]) = v;
    }
    __syncthreads();

    const int c = tid & 15, g = tid >> 4;
    const int j4 = c * 4;
    float4 acc[4][4];
#pragma unroll
    for (int m = 0; m < 4; m++)
#pragma unroll
        for (int q = 0; q < 4; q++) acc[m][q] = {0, 0, 0, 0};

    for (int k = 0; k < 64; k++) {
        float4 w0 = *(const float4*)(Wf + (size_t)k * HID + j4);
        float4 w1 = *(const float4*)(Ws + (size_t)k * HID + j4);
        float4 w2 = *(const float4*)(Wf + (size_t)(64 + k) * HID + j4);
        float4 w3 = *(const float4*)(Ws + (size_t)(64 + k) * HID + j4);
#pragma unroll
        for (int m = 0; m < 4; m++) {
            float xv = xs[g + m * 16][k];
            fma4(acc[m][0], w0, xv);
            fma4(acc[m][1], w1, xv);
            fma4(acc[m][2], w2, xv);
            fma4(acc[m][3], w3, xv);
        }
    }
#pragma unroll
    for (int m = 0; m < 4; m++) {
        int r = base + g + m * 16;
        if (r < N_NODES) {
            float* o = P + (size_t)r * 256;
            *(float4*)(o + j4)       = acc[m][0];
            *(float4*)(o + 64 + j4)  = acc[m][1];
            *(float4*)(o + 128 + j4) = acc[m][2];
            *(float4*)(o + 192 + j4) = acc[m][3];
        }
    }
}

// ---------------- edge kernel over dst-sorted order ----------------
// wave = contiguous chunk of sorted positions; register-accumulate per dst run.
__global__ __launch_bounds__(256) void cg_edge2(const float* __restrict__ P,
                                                const int* __restrict__ ei,
                                                const float* __restrict__ ea,
                                                const int* __restrict__ perm,
                                                const int* __restrict__ dst_s,
                                                const float* __restrict__ WfE,
                                                const float* __restrict__ WsE,
                                                const float* __restrict__ bf,
                                                const float* __restrict__ bs,
                                                float* __restrict__ agg) {
    const int j = threadIdx.x & 63;
    float wfe[EDIM], wse[EDIM];
#pragma unroll
    for (int k = 0; k < EDIM; k++) {
        wfe[k] = WfE[k * HID + j];
        wse[k] = WsE[k * HID + j];
    }
    const float bfv = bf[j], bsv = bs[j];
    const int wave = blockIdx.x * 4 + (threadIdx.x >> 6);
    const int nw = gridDim.x * 4;
    const int chunk = (N_EDGES + nw - 1) / nw;
    const int e0 = wave * chunk;
    const int e1 = min(e0 + chunk, N_EDGES);
    if (e0 >= e1) return;

    // prefetch first edge (scalar idx chain + vector ea row)
    int eu = __builtin_amdgcn_readfirstlane(e0);
    int d_c  = dst_s[eu];
    int pe_c = perm[eu];
    int s_c  = ei[pe_c];
    float er_c = ea[(size_t)pe_c * EDIM + (j & 31)];

    int cur = d_c;
    float pf0 = P[(size_t)cur * 256 + j];
    float ps0 = P[(size_t)cur * 256 + 64 + j];
    float acc = 0.f;

    for (int e = e0; e < e1; ++e) {
        const int d = d_c, srcn = s_c;
        const float er = er_c;
        if (e + 1 < e1) {
            int nu = __builtin_amdgcn_readfirstlane(e + 1);
            d_c  = dst_s[nu];
            pe_c = perm[nu];
            s_c  = ei[pe_c];
            er_c = ea[(size_t)pe_c * EDIM + (j & 31)];
        }
        if (d != cur) {  // uniform branch: run boundary
            unsafeAtomicAdd(&agg[(size_t)cur * HID + j], acc);
            acc = 0.f;
            cur = d;
            pf0 = P[(size_t)cur * 256 + j];
            ps0 = P[(size_t)cur * 256 + 64 + j];
        }
        const float sf = P[(size_t)srcn * 256 + 128 + j];
        const float ss = P[(size_t)srcn * 256 + 192 + j];
        float uf = bfv, us = bsv;
#pragma unroll
        for (int k = 0; k < EDIM; k++) {
            const float ek = rl_f(er, k);
            uf = fmaf(ek, wfe[k], uf);
            us = fmaf(ek, wse[k], us);
        }
        uf += pf0 + sf;
        us += ps0 + ss;
        acc += sigmoidf_(uf) * softplusf_(us);
    }
    unsafeAtomicAdd(&agg[(size_t)cur * HID + j], acc);
}

// ---------------- column stats (sum, sumsq) of agg ----------------
__global__ __launch_bounds__(256) void cg_stats(const float* __restrict__ a,
                                                double* __restrict__ st) {
    const int j = threadIdx.x & 63, rl = threadIdx.x >> 6;
    float s = 0.f, q = 0.f;
    for (int n = blockIdx.x * 4 + rl; n < N_NODES; n += gridDim.x * 4) {
        float v = a[(size_t)n * HID + j];
        s += v;
        q += v * v;
    }
    __shared__ float ls[4][64], lq[4][64];
    ls[rl][j] = s;
    lq[rl][j] = q;
    __syncthreads();
    if (threadIdx.x < 64) {
        float S = ls[0][j] + ls[1][j] + ls[2][j] + ls[3][j];
        float Q = lq[0][j] + lq[1][j] + lq[2][j] + lq[3][j];
        unsafeAtomicAdd(&st[j], (double)S);
        unsafeAtomicAdd(&st[64 + j], (double)Q);
    }
}

// ---------------- y = BN1(agg)+x (in-place into agg) ; accumulate BN2 stats ----------------
__global__ __launch_bounds__(256) void cg_bn1res(float* __restrict__ agg,
                                                 const float* __restrict__ x,
                                                 const float* __restrict__ g,
                                                 const float* __restrict__ b,
                                                 const double* __restrict__ stA,
                                                 double* __restrict__ stB) {
    const int j = threadIdx.x & 63, rl = threadIdx.x >> 6;
    const double mean = stA[j] * (1.0 / N_NODES);
    const double var  = stA[64 + j] * (1.0 / N_NODES) - mean * mean;
    const float sc = (float)((double)g[j] / sqrt(var + BN_EPS));
    const float sh = (float)((double)b[j] - mean * (double)sc);
    float s = 0.f, q = 0.f;
    for (int n = blockIdx.x * 4 + rl; n < N_NODES; n += gridDim.x * 4) {
        size_t idx = (size_t)n * HID + j;
        float v = fmaf(agg[idx], sc, sh) + x[idx];
        agg[idx] = v;
        s += v;
        q += v * v;
    }
    __shared__ float ls[4][64], lq[4][64];
    ls[rl][j] = s;
    lq[rl][j] = q;
    __syncthreads();
    if (threadIdx.x < 64) {
        float S = ls[0][j] + ls[1][j] + ls[2][j] + ls[3][j];
        float Q = lq[0][j] + lq[1][j] + lq[2][j] + lq[3][j];
        unsafeAtomicAdd(&stB[j], (double)S);
        unsafeAtomicAdd(&stB[64 + j], (double)Q);
    }
}

// ---------------- x = softplus(BN2(y)) ----------------
__global__ __launch_bounds__(256) void cg_bn2act(const float* __restrict__ agg,
                                                 float* __restrict__ x,
                                                 const float* __restrict__ g,
                                                 const float* __restrict__ b,
                                                 const double* __restrict__ stB) {
    const int j = threadIdx.x & 63, rl = threadIdx.x >> 6;
    const double mean = stB[j] * (1.0 / N_NODES);
    const double var  = stB[64 + j] * (1.0 / N_NODES) - mean * mean;
    const float sc = (float)((double)g[j] / sqrt(var + BN_EPS));
    const float sh = (float)((double)b[j] - mean * (double)sc);
    for (int n = blockIdx.x * 4 + rl; n < N_NODES; n += gridDim.x * 4) {
        size_t idx = (size_t)n * HID + j;
        x[idx] = softplusf_(fmaf(agg[idx], sc, sh));
    }
}

// ---------------- segment-mean pool ----------------
__global__ __launch_bounds__(256) void cg_pool(const float* __restrict__ x,
                                               const int* __restrict__ bid,
                                               float* __restrict__ pooled,
                                               float* __restrict__ cnt) {
    const int j = threadIdx.x & 63, rl = threadIdx.x >> 6;
    const int chunk = (N_NODES + gridDim.x - 1) / gridDim.x;
    const int s0 = blockIdx.x * chunk;
    const int e0 = min(s0 + chunk, N_NODES);
    float acc = 0.f, c = 0.f;
    int cur = -1;
    for (int n = s0 + rl; n < e0; n += 4) {
        int bg = bid[n];
        if (bg != cur) {
            if (cur >= 0) {
                unsafeAtomicAdd(&pooled[(size_t)cur * HID + j], acc);
                if (j == 0) unsafeAtomicAdd(&cnt[cur], c);
            }
            cur = bg;
            acc = 0.f;
            c = 0.f;
        }
        acc += x[(size_t)n * HID + j];
        c += 1.f;
    }
    if (cur >= 0) {
        unsafeAtomicAdd(&pooled[(size_t)cur * HID + j], acc);
        if (j == 0) unsafeAtomicAdd(&cnt[cur], c);
    }
}

// ---------------- per-graph MLP head ----------------
__global__ __launch_bounds__(64) void cg_mlp(const float* __restrict__ pooled,
                                             const float* __restrict__ cnt,
                                             const float* __restrict__ W1,
                                             const float* __restrict__ b1,
                                             const float* __restrict__ W2,
                                             const float* __restrict__ b2,
                                             float* __restrict__ out) {
    const int g = blockIdx.x;
    const int j = threadIdx.x;
    const float c = fmaxf(cnt[g], 1.f);
    const float p = pooled[(size_t)g * HID + j] / c;
    float h = b1[j];
    for (int k = 0; k < HID; k++) {
        h = fmaf(rl_f(p, k), W1[k * HID + j], h);
    }
    const float hs = h * sigmoidf_(h);  // silu
    float v = hs * W2[j];
#pragma unroll
    for (int off = 32; off > 0; off >>= 1) v += __shfl_down(v, off);
    if (j == 0) out[g] = v + b2[0];
}

extern "C" void kernel_launch(void* const* d_in, const int* in_sizes, int n_in,
                              void* d_out, int out_size, void* d_ws, size_t ws_size,
                              hipStream_t stream) {
    const int*   z   = (const int*)d_in[0];
    const int*   ei  = (const int*)d_in[1];
    const float* ea  = (const float*)d_in[2];
    const int*   bid = (const int*)d_in[3];
    const float* emb = (const float*)d_in[4];
    const float* Wf  = (const float*)d_in[5];
    const float* bf  = (const float*)d_in[6];
    const float* Ws  = (const float*)d_in[7];
    const float* bs  = (const float*)d_in[8];
    const float* gc  = (const float*)d_in[9];
    const float* bc  = (const float*)d_in[10];
    const float* go  = (const float*)d_in[11];
    const float* bo  = (const float*)d_in[12];
    const float* W1  = (const float*)d_in[13];
    const float* b1  = (const float*)d_in[14];
    const float* W2  = (const float*)d_in[15];
    const float* b2  = (const float*)d_in[16];
    float* out = (float*)d_out;

    char* ws = (char*)d_ws;
    float*  x      = (float*)(ws + X_OFF);
    float*  agg    = (float*)(ws + AGG_OFF);
    double* stA    = (double*)(ws + STA_OFF);
    double* stB    = (double*)(ws + STB_OFF);
    float*  pooled = (float*)(ws + POOL_OFF);
    float*  cnt    = (float*)(ws + CNT_OFF);
    int*    deg    = (int*)(ws + DEG_OFF);
    int*    ecur   = (int*)(ws + ECUR_OFF);
    int*    perm   = (int*)(ws + PERM_OFF);
    int*    dst_s  = (int*)(ws + DSTS_OFF);
    float*  P      = (float*)(ws + P_OFF);

    // ---- counting sort of edges by dst (once per call) ----
    (void)hipMemsetAsync(ws + DEG_OFF, 0, 400000, stream);
    cg_hist<<<(N_EDGES + 255) / 256, 256, 0, stream>>>(ei, deg);
    cg_scan<<<1, 1024, 0, stream>>>(deg, ecur);
    cg_scatter<<<(N_EDGES + 255) / 256, 256, 0, stream>>>(ei, ecur, perm, dst_s);

    cg_embed<<<(N_NODES * HID + 255) / 256, 256, 0, stream>>>(z, emb, x);

    for (int l = 0; l < LAYERS; l++) {
        const float* Wfl = Wf + (size_t)l * 160 * HID;
        const float* Wsl = Ws + (size_t)l * 160 * HID;
        // zero agg + statsA + statsB (contiguous)
        (void)hipMemsetAsync(ws + AGG_OFF, 0, 25600000 + 2048, stream);
        cg_nodeP4<<<(N_NODES + 63) / 64, 256, 0, stream>>>(x, Wfl, Wsl, P);
        cg_edge2<<<4096, 256, 0, stream>>>(P, ei, ea, perm, dst_s,
                                           Wfl + 128 * HID, Wsl + 128 * HID,
                                           bf + l * HID, bs + l * HID, agg);
        cg_stats<<<1024, 256, 0, stream>>>(agg, stA);
        cg_bn1res<<<1024, 256, 0, stream>>>(agg, x, gc + l * HID, bc + l * HID, stA, stB);
        cg_bn2act<<<1024, 256, 0, stream>>>(agg, x, go + l * HID, bo + l * HID, stB);
    }

    (void)hipMemsetAsync(ws + POOL_OFF, 0, 131072 + 2048, stream);
    cg_pool<<<1024, 256, 0, stream>>>(x, bid, pooled, cnt);
    cg_mlp<<<N_GRAPHS, 64, 0, stream>>>(pooled, cnt, W1, b1, W2, b2, out);
}

// Round 4
// 2397.576 us; speedup vs baseline: 1.0533x; 1.0397x over previous
//
#include <hip/hip_runtime.h>
#include <cstdint>
#include <cstddef>

#define N_NODES 100000
#define N_EDGES 1000000
#define N_GRAPHS 512
#define HID 64
#define EDIM 32
#define LAYERS 4
#define BN_EPS 1e-5

// ---------------- workspace layout (bytes) ----------------
static const size_t X_OFF    = 0;                                   // x: N*64 f32 (25.6 MB)
static const size_t AGG_OFF  = X_OFF + 25600000;                    // agg: N*64 f32
static const size_t STA_OFF  = AGG_OFF + 25600000;                  // statsA: 128 f64
static const size_t STB_OFF  = STA_OFF + 1024;                      // statsB: 128 f64
static const size_t POOL_OFF = STB_OFF + 1024;                      // pooled: 512*64 f32
static const size_t CNT_OFF  = POOL_OFF + 131072;                   // counts: 512 f32
static const size_t DEG_OFF  = CNT_OFF + 2048;                      // deg: N int
static const size_t ECUR_OFF = DEG_OFF + 400128;                    // ecur: N int
static const size_t PERM_OFF = ECUR_OFF + 400128;                   // perm: E int (4 MB)
static const size_t DSTS_OFF = PERM_OFF + 4000000;                  // dst_sorted: E int (4 MB)
static const size_t BSUM_OFF = DSTS_OFF + 4000000;                  // block sums: 391 int
static const size_t BOFF_OFF = BSUM_OFF + 2048;                     // block offsets: 391 int
static const size_t P_OFF    = BOFF_OFF + 2048;                     // P: N*256 f32 (102.4 MB)
// total ~162.5 MB

#define SCAN_BLOCKS 391  // ceil(100000/256)

__device__ __forceinline__ float rl_f(float v, int k) {
    return __uint_as_float(__builtin_amdgcn_readlane(__float_as_uint(v), k));
}
__device__ __forceinline__ float sigmoidf_(float x) {
    return 1.f / (1.f + __expf(-x));
}
__device__ __forceinline__ float softplusf_(float x) {
    return fmaxf(x, 0.f) + __logf(1.f + __expf(-fabsf(x)));
}
__device__ __forceinline__ void fma4(float4& a, const float4& wv, float xv) {
    a.x = fmaf(xv, wv.x, a.x);
    a.y = fmaf(xv, wv.y, a.y);
    a.z = fmaf(xv, wv.z, a.z);
    a.w = fmaf(xv, wv.w, a.w);
}

// ---------------- x = emb[z] ----------------
__global__ __launch_bounds__(256) void cg_embed(const int* __restrict__ z,
                                                const float* __restrict__ emb,
                                                float* __restrict__ x) {
    int i = blockIdx.x * 256 + threadIdx.x;
    if (i < N_NODES * HID) {
        x[i] = emb[z[i >> 6] * HID + (i & 63)];
    }
}

// ---------------- counting sort by dst: histogram ----------------
__global__ __launch_bounds__(256) void cg_hist(const int* __restrict__ ei,
                                               int* __restrict__ deg) {
    int e = blockIdx.x * 256 + threadIdx.x;
    if (e < N_EDGES) atomicAdd(&deg[ei[N_EDGES + e]], 1);
}

// ---------------- scan stage 1: per-block sums (coalesced) ----------------
__global__ __launch_bounds__(256) void cg_bsum(const int* __restrict__ deg,
                                               int* __restrict__ bsum) {
    const int i = blockIdx.x * 256 + threadIdx.x;
    int v = (i < N_NODES) ? deg[i] : 0;
#pragma unroll
    for (int off = 32; off > 0; off >>= 1) v += __shfl_down(v, off);
    __shared__ int wsum[4];
    if ((threadIdx.x & 63) == 0) wsum[threadIdx.x >> 6] = v;
    __syncthreads();
    if (threadIdx.x == 0) bsum[blockIdx.x] = wsum[0] + wsum[1] + wsum[2] + wsum[3];
}

// ---------------- scan stage 2: scan of block sums (1 block) ----------------
__global__ __launch_bounds__(512) void cg_bscan(const int* __restrict__ bsum,
                                                int* __restrict__ boff) {
    __shared__ int ps[512];
    const int t = threadIdx.x;
    int v = (t < SCAN_BLOCKS) ? bsum[t] : 0;
    ps[t] = v;
    __syncthreads();
    for (int off = 1; off < 512; off <<= 1) {
        int u = (t >= off) ? ps[t - off] : 0;
        __syncthreads();
        ps[t] += u;
        __syncthreads();
    }
    if (t < SCAN_BLOCKS) boff[t] = ps[t] - v;  // exclusive
}

// ---------------- scan stage 3: per-element exclusive scan ----------------
__global__ __launch_bounds__(256) void cg_escan(const int* __restrict__ deg,
                                                const int* __restrict__ boff,
                                                int* __restrict__ ecur) {
    __shared__ int ps[256];
    const int t = threadIdx.x;
    const int i = blockIdx.x * 256 + t;
    int v = (i < N_NODES) ? deg[i] : 0;
    ps[t] = v;
    __syncthreads();
    for (int off = 1; off < 256; off <<= 1) {
        int u = (t >= off) ? ps[t - off] : 0;
        __syncthreads();
        ps[t] += u;
        __syncthreads();
    }
    if (i < N_NODES) ecur[i] = ps[t] - v + boff[blockIdx.x];
}

// ---------------- scatter: perm[pos]=edge, dst_s[pos]=dst ----------------
__global__ __launch_bounds__(256) void cg_scatter(const int* __restrict__ ei,
                                                  int* __restrict__ ecur,
                                                  int* __restrict__ perm,
                                                  int* __restrict__ dst_s) {
    int e = blockIdx.x * 256 + threadIdx.x;
    if (e < N_EDGES) {
        int d = ei[N_EDGES + e];
        int pos = atomicAdd(&ecur[d], 1);
        perm[pos] = e;
        dst_s[pos] = d;
    }
}

// ---------------- P = x @ [Wf(0:64)|Ws(0:64)|Wf(64:128)|Ws(64:128)] ----------------
__global__ __launch_bounds__(256, 4) void cg_nodeP4(const float* __restrict__ x,
                                                    const float* __restrict__ Wf,
                                                    const float* __restrict__ Ws,
                                                    float* __restrict__ P) {
    __shared__ __align__(16) float xs[64][68];
    const int tid = threadIdx.x;
    const int base = blockIdx.x * 64;
#pragma unroll
    for (int i = 0; i < 4; i++) {
        int f4 = tid * 4 + i;           // 0..1023 over [64 rows][16 float4]
        int r = f4 >> 4, c4 = (f4 & 15) * 4;
        float4 v = {0, 0, 0, 0};
        if (base + r < N_NODES) v = *(const float4*)(x + (size_t)(base + r) * HID + c4);
        *(float4*)(&xs[r][c4]) = v;
    }
    __syncthreads();

    const int g = tid >> 4;
    const int j4 = (tid & 15) * 4;
    float4 acc[4][4];
#pragma unroll
    for (int m = 0; m < 4; m++)
#pragma unroll
        for (int q = 0; q < 4; q++) acc[m][q] = {0, 0, 0, 0};

    for (int k = 0; k < 64; k++) {
        float4 w0 = *(const float4*)(Wf + (size_t)k * HID + j4);
        float4 w1 = *(const float4*)(Ws + (size_t)k * HID + j4);
        float4 w2 = *(const float4*)(Wf + (size_t)(64 + k) * HID + j4);
        float4 w3 = *(const float4*)(Ws + (size_t)(64 + k) * HID + j4);
#pragma unroll
        for (int m = 0; m < 4; m++) {
            float xv = xs[g + m * 16][k];
            fma4(acc[m][0], w0, xv);
            fma4(acc[m][1], w1, xv);
            fma4(acc[m][2], w2, xv);
            fma4(acc[m][3], w3, xv);
        }
    }
#pragma unroll
    for (int m = 0; m < 4; m++) {
        int r = base + g + m * 16;
        if (r < N_NODES) {
            float* o = P + (size_t)r * 256;
            *(float4*)(o + j4)       = acc[m][0];
            *(float4*)(o + 64 + j4)  = acc[m][1];
            *(float4*)(o + 128 + j4) = acc[m][2];
            *(float4*)(o + 192 + j4) = acc[m][3];
        }
    }
}

// ---------------- edge kernel over dst-sorted order ----------------
// All per-edge index/attr data is wave-uniform (scalar loads); weights resident
// in VGPRs (launch_bounds caps occupancy at 4 blocks/CU -> 128 VGPR budget).
__global__ __launch_bounds__(256, 4) void cg_edge3(const float* __restrict__ P,
                                                   const int* __restrict__ ei,
                                                   const float* __restrict__ ea,
                                                   const int* __restrict__ perm,
                                                   const int* __restrict__ dst_s,
                                                   const float* __restrict__ WfE,
                                                   const float* __restrict__ WsE,
                                                   const float* __restrict__ bf,
                                                   const float* __restrict__ bs,
                                                   float* __restrict__ agg) {
    const int j = threadIdx.x & 63;
    float wfe[EDIM], wse[EDIM];
#pragma unroll
    for (int k = 0; k < EDIM; k++) {
        wfe[k] = WfE[k * HID + j];
        wse[k] = WsE[k * HID + j];
    }
    const float bfv = bf[j], bsv = bs[j];
    const int wave = blockIdx.x * 4 + (threadIdx.x >> 6);
    const int nw = gridDim.x * 4;
    const int chunk = (N_EDGES + nw - 1) / nw;
    const int e0 = wave * chunk;
    const int e1 = min(e0 + chunk, N_EDGES);
    if (e0 >= e1) return;

    int cur = __builtin_amdgcn_readfirstlane(dst_s[e0]);
    float pf0 = P[(size_t)cur * 256 + j];
    float ps0 = P[(size_t)cur * 256 + 64 + j];
    float acc = 0.f;

    for (int e = e0; e < e1; ++e) {
        const int d  = __builtin_amdgcn_readfirstlane(dst_s[e]);
        const int pe = __builtin_amdgcn_readfirstlane(perm[e]);
        if (d != cur) {  // uniform branch: run boundary
            unsafeAtomicAdd(&agg[(size_t)cur * HID + j], acc);
            acc = 0.f;
            cur = d;
            pf0 = P[(size_t)cur * 256 + j];
            ps0 = P[(size_t)cur * 256 + 64 + j];
        }
        const int s = __builtin_amdgcn_readfirstlane(ei[pe]);
        const float sf = P[(size_t)s * 256 + 128 + j];
        const float ss = P[(size_t)s * 256 + 192 + j];
        const float* __restrict__ earow = ea + (size_t)pe * EDIM;
        float uf = bfv + pf0 + sf;
        float us = bsv + ps0 + ss;
#pragma unroll
        for (int k = 0; k < EDIM; k++) {
            const float ek = earow[k];  // wave-uniform -> s_load
            uf = fmaf(ek, wfe[k], uf);
            us = fmaf(ek, wse[k], us);
        }
        acc += sigmoidf_(uf) * softplusf_(us);
    }
    unsafeAtomicAdd(&agg[(size_t)cur * HID + j], acc);
}

// ---------------- column stats (sum, sumsq) of agg ; zero stB for bn1res ----------------
__global__ __launch_bounds__(256) void cg_stats(const float* __restrict__ a,
                                                double* __restrict__ stA,
                                                double* __restrict__ stB) {
    if (blockIdx.x == 0 && threadIdx.x < 128) stB[threadIdx.x] = 0.0;
    const int j = threadIdx.x & 63, rl = threadIdx.x >> 6;
    float s = 0.f, q = 0.f;
    for (int n = blockIdx.x * 4 + rl; n < N_NODES; n += gridDim.x * 4) {
        float v = a[(size_t)n * HID + j];
        s += v;
        q += v * v;
    }
    __shared__ float ls[4][64], lq[4][64];
    ls[rl][j] = s;
    lq[rl][j] = q;
    __syncthreads();
    if (threadIdx.x < 64) {
        float S = ls[0][j] + ls[1][j] + ls[2][j] + ls[3][j];
        float Q = lq[0][j] + lq[1][j] + lq[2][j] + lq[3][j];
        unsafeAtomicAdd(&stA[j], (double)S);
        unsafeAtomicAdd(&stA[64 + j], (double)Q);
    }
}

// ---------------- y = BN1(agg)+x (in-place into agg) ; accumulate BN2 stats ----------------
__global__ __launch_bounds__(256) void cg_bn1res(float* __restrict__ agg,
                                                 const float* __restrict__ x,
                                                 const float* __restrict__ g,
                                                 const float* __restrict__ b,
                                                 const double* __restrict__ stA,
                                                 double* __restrict__ stB) {
    const int j = threadIdx.x & 63, rl = threadIdx.x >> 6;
    const double mean = stA[j] * (1.0 / N_NODES);
    const double var  = stA[64 + j] * (1.0 / N_NODES) - mean * mean;
    const float sc = (float)((double)g[j] / sqrt(var + BN_EPS));
    const float sh = (float)((double)b[j] - mean * (double)sc);
    float s = 0.f, q = 0.f;
    for (int n = blockIdx.x * 4 + rl; n < N_NODES; n += gridDim.x * 4) {
        size_t idx = (size_t)n * HID + j;
        float v = fmaf(agg[idx], sc, sh) + x[idx];
        agg[idx] = v;
        s += v;
        q += v * v;
    }
    __shared__ float ls[4][64], lq[4][64];
    ls[rl][j] = s;
    lq[rl][j] = q;
    __syncthreads();
    if (threadIdx.x < 64) {
        float S = ls[0][j] + ls[1][j] + ls[2][j] + ls[3][j];
        float Q = lq[0][j] + lq[1][j] + lq[2][j] + lq[3][j];
        unsafeAtomicAdd(&stB[j], (double)S);
        unsafeAtomicAdd(&stB[64 + j], (double)Q);
    }
}

// ---------------- x = softplus(BN2(y)) ; zero agg + stA for next layer ----------------
__global__ __launch_bounds__(256) void cg_bn2act(float* __restrict__ agg,
                                                 float* __restrict__ x,
                                                 const float* __restrict__ g,
                                                 const float* __restrict__ b,
                                                 const double* __restrict__ stB,
                                                 double* __restrict__ stA) {
    if (blockIdx.x == 0 && threadIdx.x < 128) stA[threadIdx.x] = 0.0;
    const int j = threadIdx.x & 63, rl = threadIdx.x >> 6;
    const double mean = stB[j] * (1.0 / N_NODES);
    const double var  = stB[64 + j] * (1.0 / N_NODES) - mean * mean;
    const float sc = (float)((double)g[j] / sqrt(var + BN_EPS));
    const float sh = (float)((double)b[j] - mean * (double)sc);
    for (int n = blockIdx.x * 4 + rl; n < N_NODES; n += gridDim.x * 4) {
        size_t idx = (size_t)n * HID + j;
        x[idx] = softplusf_(fmaf(agg[idx], sc, sh));
        agg[idx] = 0.f;  // ready for next layer's scatter-add
    }
}

// ---------------- segment-mean pool ----------------
__global__ __launch_bounds__(256) void cg_pool(const float* __restrict__ x,
                                               const int* __restrict__ bid,
                                               float* __restrict__ pooled,
                                               float* __restrict__ cnt) {
    const int j = threadIdx.x & 63, rl = threadIdx.x >> 6;
    const int chunk = (N_NODES + gridDim.x - 1) / gridDim.x;
    const int s0 = blockIdx.x * chunk;
    const int e0 = min(s0 + chunk, N_NODES);
    float acc = 0.f, c = 0.f;
    int cur = -1;
    for (int n = s0 + rl; n < e0; n += 4) {
        int bg = bid[n];
        if (bg != cur) {
            if (cur >= 0) {
                unsafeAtomicAdd(&pooled[(size_t)cur * HID + j], acc);
                if (j == 0) unsafeAtomicAdd(&cnt[cur], c);
            }
            cur = bg;
            acc = 0.f;
            c = 0.f;
        }
        acc += x[(size_t)n * HID + j];
        c += 1.f;
    }
    if (cur >= 0) {
        unsafeAtomicAdd(&pooled[(size_t)cur * HID + j], acc);
        if (j == 0) unsafeAtomicAdd(&cnt[cur], c);
    }
}

// ---------------- per-graph MLP head ----------------
__global__ __launch_bounds__(64) void cg_mlp(const float* __restrict__ pooled,
                                             const float* __restrict__ cnt,
                                             const float* __restrict__ W1,
                                             const float* __restrict__ b1,
                                             const float* __restrict__ W2,
                                             const float* __restrict__ b2,
                                             float* __restrict__ out) {
    const int g = blockIdx.x;
    const int j = threadIdx.x;
    const float c = fmaxf(cnt[g], 1.f);
    const float p = pooled[(size_t)g * HID + j] / c;
    float h = b1[j];
    for (int k = 0; k < HID; k++) {
        h = fmaf(rl_f(p, k), W1[k * HID + j], h);
    }
    const float hs = h * sigmoidf_(h);  // silu
    float v = hs * W2[j];
#pragma unroll
    for (int off = 32; off > 0; off >>= 1) v += __shfl_down(v, off);
    if (j == 0) out[g] = v + b2[0];
}

extern "C" void kernel_launch(void* const* d_in, const int* in_sizes, int n_in,
                              void* d_out, int out_size, void* d_ws, size_t ws_size,
                              hipStream_t stream) {
    const int*   z   = (const int*)d_in[0];
    const int*   ei  = (const int*)d_in[1];
    const float* ea  = (const float*)d_in[2];
    const int*   bid = (const int*)d_in[3];
    const float* emb = (const float*)d_in[4];
    const float* Wf  = (const float*)d_in[5];
    const float* bf  = (const float*)d_in[6];
    const float* Ws  = (const float*)d_in[7];
    const float* bs  = (const float*)d_in[8];
    const float* gc  = (const float*)d_in[9];
    const float* bc  = (const float*)d_in[10];
    const float* go  = (const float*)d_in[11];
    const float* bo  = (const float*)d_in[12];
    const float* W1  = (const float*)d_in[13];
    const float* b1  = (const float*)d_in[14];
    const float* W2  = (const float*)d_in[15];
    const float* b2  = (const float*)d_in[16];
    float* out = (float*)d_out;

    char* ws = (char*)d_ws;
    float*  x      = (float*)(ws + X_OFF);
    float*  agg    = (float*)(ws + AGG_OFF);
    double* stA    = (double*)(ws + STA_OFF);
    double* stB    = (double*)(ws + STB_OFF);
    float*  pooled = (float*)(ws + POOL_OFF);
    float*  cnt    = (float*)(ws + CNT_OFF);
    int*    deg    = (int*)(ws + DEG_OFF);
    int*    ecur   = (int*)(ws + ECUR_OFF);
    int*    perm   = (int*)(ws + PERM_OFF);
    int*    dst_s  = (int*)(ws + DSTS_OFF);
    int*    bsum   = (int*)(ws + BSUM_OFF);
    int*    boff   = (int*)(ws + BOFF_OFF);
    float*  P      = (float*)(ws + P_OFF);

    // zero agg+stats (layer 0) and pool buffers up front
    (void)hipMemsetAsync(ws + AGG_OFF, 0, 25600000 + 2048, stream);
    (void)hipMemsetAsync(ws + POOL_OFF, 0, 131072 + 2048, stream);
    (void)hipMemsetAsync(ws + DEG_OFF, 0, 400000, stream);

    // ---- counting sort of edges by dst (once per call) ----
    cg_hist<<<(N_EDGES + 255) / 256, 256, 0, stream>>>(ei, deg);
    cg_bsum<<<SCAN_BLOCKS, 256, 0, stream>>>(deg, bsum);
    cg_bscan<<<1, 512, 0, stream>>>(bsum, boff);
    cg_escan<<<SCAN_BLOCKS, 256, 0, stream>>>(deg, boff, ecur);
    cg_scatter<<<(N_EDGES + 255) / 256, 256, 0, stream>>>(ei, ecur, perm, dst_s);

    cg_embed<<<(N_NODES * HID + 255) / 256, 256, 0, stream>>>(z, emb, x);

    for (int l = 0; l < LAYERS; l++) {
        const float* Wfl = Wf + (size_t)l * 160 * HID;
        const float* Wsl = Ws + (size_t)l * 160 * HID;
        cg_nodeP4<<<(N_NODES + 63) / 64, 256, 0, stream>>>(x, Wfl, Wsl, P);
        cg_edge3<<<2048, 256, 0, stream>>>(P, ei, ea, perm, dst_s,
                                           Wfl + 128 * HID, Wsl + 128 * HID,
                                           bf + l * HID, bs + l * HID, agg);
        cg_stats<<<1024, 256, 0, stream>>>(agg, stA, stB);
        cg_bn1res<<<1024, 256, 0, stream>>>(agg, x, gc + l * HID, bc + l * HID, stA, stB);
        cg_bn2act<<<1024, 256, 0, stream>>>(agg, x, go + l * HID, bo + l * HID, stB, stA);
    }

    cg_pool<<<1024, 256, 0, stream>>>(x, bid, pooled, cnt);
    cg_mlp<<<N_GRAPHS, 64, 0, stream>>>(pooled, cnt, W1, b1, W2, b2, out);
}

// Round 5
// 2202.723 us; speedup vs baseline: 1.1465x; 1.0885x over previous
//
#include <hip/hip_runtime.h>
#include <cstdint>
#include <cstddef>

#define N_NODES 100000
#define N_EDGES 1000000
#define N_GRAPHS 512
#define HID 64
#define EDIM 32
#define LAYERS 4
#define BN_EPS 1e-5
#define NPB 1024  // partial blocks for stats/bn kernels

// ---------------- workspace layout (bytes) ----------------
static const size_t X_OFF    = 0;          // x: N*64 f32 (25.6 MB)
static const size_t AGG_OFF  = 25600000;   // agg: N*64 f32
static const size_t STA_OFF  = 51200000;   // statsA: 128 f64
static const size_t STB_OFF  = 51201024;   // statsB: 128 f64
static const size_t POOL_OFF = 51202048;   // pooled: 512*64 f32
static const size_t CNT_OFF  = 51333120;   // counts: 512 f32
static const size_t DEG_OFF  = 51335168;   // deg: N int
static const size_t ECUR_OFF = 51735296;   // ecur: N int
static const size_t PERM_OFF = 52135424;   // perm: E int (4 MB)
static const size_t DSTS_OFF = 56135424;   // dst_sorted: E int (4 MB)
static const size_t SRCS_OFF = 60135424;   // src_sorted: E int (4 MB)
static const size_t BSUM_OFF = 64135424;   // block sums
static const size_t BOFF_OFF = 64137472;   // block offsets
static const size_t PART_OFF = 64139520;   // partials: NPB*128 f32 (512 KB)
static const size_t P_OFF    = 64663808;   // P: N*256 f32 (102.4 MB)
// total ~167.1 MB

#define SCAN_BLOCKS 391  // ceil(100000/256)

__device__ __forceinline__ float rl_f(float v, int k) {
    return __uint_as_float(__builtin_amdgcn_readlane(__float_as_uint(v), k));
}
__device__ __forceinline__ float sigmoidf_(float x) {
    return 1.f / (1.f + __expf(-x));
}
__device__ __forceinline__ float softplusf_(float x) {
    return fmaxf(x, 0.f) + __logf(1.f + __expf(-fabsf(x)));
}
__device__ __forceinline__ void fma4(float4& a, const float4& wv, float xv) {
    a.x = fmaf(xv, wv.x, a.x);
    a.y = fmaf(xv, wv.y, a.y);
    a.z = fmaf(xv, wv.z, a.z);
    a.w = fmaf(xv, wv.w, a.w);
}

// ---------------- x = emb[z] ----------------
__global__ __launch_bounds__(256) void cg_embed(const int* __restrict__ z,
                                                const float* __restrict__ emb,
                                                float* __restrict__ x) {
    int i = blockIdx.x * 256 + threadIdx.x;
    if (i < N_NODES * HID) {
        x[i] = emb[z[i >> 6] * HID + (i & 63)];
    }
}

// ---------------- counting sort by dst: histogram ----------------
__global__ __launch_bounds__(256) void cg_hist(const int* __restrict__ ei,
                                               int* __restrict__ deg) {
    int e = blockIdx.x * 256 + threadIdx.x;
    if (e < N_EDGES) atomicAdd(&deg[ei[N_EDGES + e]], 1);
}

// ---------------- scan stage 1: per-block sums ----------------
__global__ __launch_bounds__(256) void cg_bsum(const int* __restrict__ deg,
                                               int* __restrict__ bsum) {
    const int i = blockIdx.x * 256 + threadIdx.x;
    int v = (i < N_NODES) ? deg[i] : 0;
#pragma unroll
    for (int off = 32; off > 0; off >>= 1) v += __shfl_down(v, off);
    __shared__ int wsum[4];
    if ((threadIdx.x & 63) == 0) wsum[threadIdx.x >> 6] = v;
    __syncthreads();
    if (threadIdx.x == 0) bsum[blockIdx.x] = wsum[0] + wsum[1] + wsum[2] + wsum[3];
}

// ---------------- scan stage 2: scan of block sums (1 block) ----------------
__global__ __launch_bounds__(512) void cg_bscan(const int* __restrict__ bsum,
                                                int* __restrict__ boff) {
    __shared__ int ps[512];
    const int t = threadIdx.x;
    int v = (t < SCAN_BLOCKS) ? bsum[t] : 0;
    ps[t] = v;
    __syncthreads();
    for (int off = 1; off < 512; off <<= 1) {
        int u = (t >= off) ? ps[t - off] : 0;
        __syncthreads();
        ps[t] += u;
        __syncthreads();
    }
    if (t < SCAN_BLOCKS) boff[t] = ps[t] - v;  // exclusive
}

// ---------------- scan stage 3: per-element exclusive scan ----------------
__global__ __launch_bounds__(256) void cg_escan(const int* __restrict__ deg,
                                                const int* __restrict__ boff,
                                                int* __restrict__ ecur) {
    __shared__ int ps[256];
    const int t = threadIdx.x;
    const int i = blockIdx.x * 256 + t;
    int v = (i < N_NODES) ? deg[i] : 0;
    ps[t] = v;
    __syncthreads();
    for (int off = 1; off < 256; off <<= 1) {
        int u = (t >= off) ? ps[t - off] : 0;
        __syncthreads();
        ps[t] += u;
        __syncthreads();
    }
    if (i < N_NODES) ecur[i] = ps[t] - v + boff[blockIdx.x];
}

// ---------------- scatter: perm/dst/src at sorted position ----------------
__global__ __launch_bounds__(256) void cg_scatter(const int* __restrict__ ei,
                                                  int* __restrict__ ecur,
                                                  int* __restrict__ perm,
                                                  int* __restrict__ dst_s,
                                                  int* __restrict__ src_s) {
    int e = blockIdx.x * 256 + threadIdx.x;
    if (e < N_EDGES) {
        int d = ei[N_EDGES + e];
        int pos = atomicAdd(&ecur[d], 1);
        perm[pos] = e;
        dst_s[pos] = d;
        src_s[pos] = ei[e];
    }
}

// ---------------- P = x @ [Wf(0:64)|Ws(0:64)|Wf(64:128)|Ws(64:128)] ----------------
__global__ __launch_bounds__(256, 2) void cg_nodeP4(const float* __restrict__ x,
                                                    const float* __restrict__ Wf,
                                                    const float* __restrict__ Ws,
                                                    float* __restrict__ P) {
    __shared__ __align__(16) float xs[64][68];
    const int tid = threadIdx.x;
    const int base = blockIdx.x * 64;
#pragma unroll
    for (int i = 0; i < 4; i++) {
        int f4 = tid * 4 + i;           // 0..1023 over [64 rows][16 float4]
        int r = f4 >> 4, c4 = (f4 & 15) * 4;
        float4 v = {0, 0, 0, 0};
        if (base + r < N_NODES) v = *(const float4*)(x + (size_t)(base + r) * HID + c4);
        *(float4*)(&xs[r][c4]) = v;
    }
    __syncthreads();

    const int g = tid >> 4;
    const int j4 = (tid & 15) * 4;
    float4 acc[4][4];
#pragma unroll
    for (int m = 0; m < 4; m++)
#pragma unroll
        for (int q = 0; q < 4; q++) acc[m][q] = {0, 0, 0, 0};

    for (int k = 0; k < 64; k++) {
        float4 w0 = *(const float4*)(Wf + (size_t)k * HID + j4);
        float4 w1 = *(const float4*)(Ws + (size_t)k * HID + j4);
        float4 w2 = *(const float4*)(Wf + (size_t)(64 + k) * HID + j4);
        float4 w3 = *(const float4*)(Ws + (size_t)(64 + k) * HID + j4);
#pragma unroll
        for (int m = 0; m < 4; m++) {
            float xv = xs[g + m * 16][k];
            fma4(acc[m][0], w0, xv);
            fma4(acc[m][1], w1, xv);
            fma4(acc[m][2], w2, xv);
            fma4(acc[m][3], w3, xv);
        }
    }
#pragma unroll
    for (int m = 0; m < 4; m++) {
        int r = base + g + m * 16;
        if (r < N_NODES) {
            float* o = P + (size_t)r * 256;
            *(float4*)(o + j4)       = acc[m][0];
            *(float4*)(o + 64 + j4)  = acc[m][1];
            *(float4*)(o + 128 + j4) = acc[m][2];
            *(float4*)(o + 192 + j4) = acc[m][3];
        }
    }
}

// ---------------- edge kernel: sorted streams + register-pinned weights ----------------
__global__ __launch_bounds__(256, 4) void cg_edge4(const float* __restrict__ P,
                                                   const float* __restrict__ ea,
                                                   const int* __restrict__ perm,
                                                   const int* __restrict__ dst_s,
                                                   const int* __restrict__ src_s,
                                                   const float* __restrict__ WfE,
                                                   const float* __restrict__ WsE,
                                                   const float* __restrict__ bf,
                                                   const float* __restrict__ bs,
                                                   float* __restrict__ agg) {
    const int j = threadIdx.x & 63;
    float wfe[EDIM], wse[EDIM];
#pragma unroll
    for (int k = 0; k < EDIM; k++) wfe[k] = WfE[k * HID + j];
#pragma unroll
    for (int k = 0; k < EDIM; k++) wse[k] = WsE[k * HID + j];
    // Pin weights in VGPRs: opaque asm stops the compiler from sinking the
    // loads back into the edge loop (round-4 disasm evidence: VGPR=48 -> remat).
#pragma unroll
    for (int k = 0; k < EDIM; k++) {
        asm volatile("" : "+v"(wfe[k]));
        asm volatile("" : "+v"(wse[k]));
    }
    const float bfv = bf[j], bsv = bs[j];

    const int wave = blockIdx.x * 4 + (threadIdx.x >> 6);
    const int nw = gridDim.x * 4;
    const int chunk = (N_EDGES + nw - 1) / nw;
    const int e0 = wave * chunk;
    const int e1 = min(e0 + chunk, N_EDGES);
    if (e0 >= e1) return;

    // prefetched state for edge e
    int eu = __builtin_amdgcn_readfirstlane(e0);
    int d_c  = dst_s[eu];
    int s_c  = src_s[eu];
    int pe_c = perm[eu];
    float sf_c = P[(size_t)s_c * 256 + 128 + j];
    float ss_c = P[(size_t)s_c * 256 + 192 + j];

    int cur = __builtin_amdgcn_readfirstlane(d_c);
    float pf0 = P[(size_t)cur * 256 + j];
    float ps0 = P[(size_t)cur * 256 + 64 + j];
    float acc = 0.f;

    for (int e = e0; e < e1; ++e) {
        const int d  = __builtin_amdgcn_readfirstlane(d_c);
        const int pe = __builtin_amdgcn_readfirstlane(pe_c);
        const float sf = sf_c, ss = ss_c;
        // current ea row (uniform address -> s_load_dwordx16 x2), issued early
        const float* __restrict__ er = ea + (size_t)pe * EDIM;
        float e_r[EDIM];
#pragma unroll
        for (int k = 0; k < EDIM; k++) e_r[k] = er[k];
        // prefetch edge e+1 (sequential index streams + random P gather)
        if (e + 1 < e1) {
            int nu = __builtin_amdgcn_readfirstlane(e + 1);
            d_c  = dst_s[nu];
            s_c  = src_s[nu];
            pe_c = perm[nu];
            sf_c = P[(size_t)s_c * 256 + 128 + j];
            ss_c = P[(size_t)s_c * 256 + 192 + j];
        }
        if (d != cur) {  // run boundary (wave-uniform)
            unsafeAtomicAdd(&agg[(size_t)cur * HID + j], acc);
            acc = 0.f;
            cur = d;
            pf0 = P[(size_t)cur * 256 + j];
            ps0 = P[(size_t)cur * 256 + 64 + j];
        }
        float uf0 = bfv + pf0, uf1 = sf;
        float us0 = bsv + ps0, us1 = ss;
#pragma unroll
        for (int k = 0; k < EDIM; k += 2) {
            uf0 = fmaf(e_r[k], wfe[k], uf0);
            us0 = fmaf(e_r[k], wse[k], us0);
            uf1 = fmaf(e_r[k + 1], wfe[k + 1], uf1);
            us1 = fmaf(e_r[k + 1], wse[k + 1], us1);
        }
        acc += sigmoidf_(uf0 + uf1) * softplusf_(us0 + us1);
    }
    unsafeAtomicAdd(&agg[(size_t)cur * HID + j], acc);
}

// ---------------- column stats of agg -> per-block partials ----------------
__global__ __launch_bounds__(256) void cg_stats(const float* __restrict__ a,
                                                float* __restrict__ parts) {
    const int j = threadIdx.x & 63, rl = threadIdx.x >> 6;
    float s = 0.f, q = 0.f;
    for (int n = blockIdx.x * 4 + rl; n < N_NODES; n += gridDim.x * 4) {
        float v = a[(size_t)n * HID + j];
        s += v;
        q += v * v;
    }
    __shared__ float ls[4][64], lq[4][64];
    ls[rl][j] = s;
    lq[rl][j] = q;
    __syncthreads();
    if (threadIdx.x < 64) {
        float S = ls[0][j] + ls[1][j] + ls[2][j] + ls[3][j];
        float Q = lq[0][j] + lq[1][j] + lq[2][j] + lq[3][j];
        parts[(size_t)blockIdx.x * 128 + j] = S;
        parts[(size_t)blockIdx.x * 128 + 64 + j] = Q;
    }
}

// ---------------- finalize: st[c] = sum_b parts[b][c] (f64) ----------------
__global__ __launch_bounds__(256) void cg_fin(const float* __restrict__ parts,
                                              double* __restrict__ st) {
    const int c = threadIdx.x & 127;  // column 0..127
    const int h = threadIdx.x >> 7;   // half 0/1
    double s = 0.0;
    for (int i = h * (NPB / 2); i < (h + 1) * (NPB / 2); i++)
        s += (double)parts[(size_t)i * 128 + c];
    __shared__ double sh[128];
    if (h == 0) sh[c] = s;
    __syncthreads();
    if (h == 1) st[c] = sh[c] + s;
}

// ---------------- y = BN1(agg)+x (in-place) ; BN2 partials ----------------
__global__ __launch_bounds__(256) void cg_bn1res(float* __restrict__ agg,
                                                 const float* __restrict__ x,
                                                 const float* __restrict__ g,
                                                 const float* __restrict__ b,
                                                 const double* __restrict__ stA,
                                                 float* __restrict__ parts) {
    const int j = threadIdx.x & 63, rl = threadIdx.x >> 6;
    const double mean = stA[j] * (1.0 / N_NODES);
    const double var  = stA[64 + j] * (1.0 / N_NODES) - mean * mean;
    const float sc = (float)((double)g[j] / sqrt(var + BN_EPS));
    const float sh = (float)((double)b[j] - mean * (double)sc);
    float s = 0.f, q = 0.f;
    for (int n = blockIdx.x * 4 + rl; n < N_NODES; n += gridDim.x * 4) {
        size_t idx = (size_t)n * HID + j;
        float v = fmaf(agg[idx], sc, sh) + x[idx];
        agg[idx] = v;
        s += v;
        q += v * v;
    }
    __shared__ float ls[4][64], lq[4][64];
    ls[rl][j] = s;
    lq[rl][j] = q;
    __syncthreads();
    if (threadIdx.x < 64) {
        float S = ls[0][j] + ls[1][j] + ls[2][j] + ls[3][j];
        float Q = lq[0][j] + lq[1][j] + lq[2][j] + lq[3][j];
        parts[(size_t)blockIdx.x * 128 + j] = S;
        parts[(size_t)blockIdx.x * 128 + 64 + j] = Q;
    }
}

// ---------------- x = softplus(BN2(y)) ; zero agg for next layer ----------------
__global__ __launch_bounds__(256) void cg_bn2act(float* __restrict__ agg,
                                                 float* __restrict__ x,
                                                 const float* __restrict__ g,
                                                 const float* __restrict__ b,
                                                 const double* __restrict__ stB) {
    const int j = threadIdx.x & 63, rl = threadIdx.x >> 6;
    const double mean = stB[j] * (1.0 / N_NODES);
    const double var  = stB[64 + j] * (1.0 / N_NODES) - mean * mean;
    const float sc = (float)((double)g[j] / sqrt(var + BN_EPS));
    const float sh = (float)((double)b[j] - mean * (double)sc);
    for (int n = blockIdx.x * 4 + rl; n < N_NODES; n += gridDim.x * 4) {
        size_t idx = (size_t)n * HID + j;
        x[idx] = softplusf_(fmaf(agg[idx], sc, sh));
        agg[idx] = 0.f;  // ready for next layer's scatter-add
    }
}

// ---------------- segment-mean pool ----------------
__global__ __launch_bounds__(256) void cg_pool(const float* __restrict__ x,
                                               const int* __restrict__ bid,
                                               float* __restrict__ pooled,
                                               float* __restrict__ cnt) {
    const int j = threadIdx.x & 63, rl = threadIdx.x >> 6;
    const int chunk = (N_NODES + gridDim.x - 1) / gridDim.x;
    const int s0 = blockIdx.x * chunk;
    const int e0 = min(s0 + chunk, N_NODES);
    float acc = 0.f, c = 0.f;
    int cur = -1;
    for (int n = s0 + rl; n < e0; n += 4) {
        int bg = bid[n];
        if (bg != cur) {
            if (cur >= 0) {
                unsafeAtomicAdd(&pooled[(size_t)cur * HID + j], acc);
                if (j == 0) unsafeAtomicAdd(&cnt[cur], c);
            }
            cur = bg;
            acc = 0.f;
            c = 0.f;
        }
        acc += x[(size_t)n * HID + j];
        c += 1.f;
    }
    if (cur >= 0) {
        unsafeAtomicAdd(&pooled[(size_t)cur * HID + j], acc);
        if (j == 0) unsafeAtomicAdd(&cnt[cur], c);
    }
}

// ---------------- per-graph MLP head ----------------
__global__ __launch_bounds__(64) void cg_mlp(const float* __restrict__ pooled,
                                             const float* __restrict__ cnt,
                                             const float* __restrict__ W1,
                                             const float* __restrict__ b1,
                                             const float* __restrict__ W2,
                                             const float* __restrict__ b2,
                                             float* __restrict__ out) {
    const int g = blockIdx.x;
    const int j = threadIdx.x;
    const float c = fmaxf(cnt[g], 1.f);
    const float p = pooled[(size_t)g * HID + j] / c;
    float h = b1[j];
    for (int k = 0; k < HID; k++) {
        h = fmaf(rl_f(p, k), W1[k * HID + j], h);
    }
    const float hs = h * sigmoidf_(h);  // silu
    float v = hs * W2[j];
#pragma unroll
    for (int off = 32; off > 0; off >>= 1) v += __shfl_down(v, off);
    if (j == 0) out[g] = v + b2[0];
}

extern "C" void kernel_launch(void* const* d_in, const int* in_sizes, int n_in,
                              void* d_out, int out_size, void* d_ws, size_t ws_size,
                              hipStream_t stream) {
    const int*   z   = (const int*)d_in[0];
    const int*   ei  = (const int*)d_in[1];
    const float* ea  = (const float*)d_in[2];
    const int*   bid = (const int*)d_in[3];
    const float* emb = (const float*)d_in[4];
    const float* Wf  = (const float*)d_in[5];
    const float* bf  = (const float*)d_in[6];
    const float* Ws  = (const float*)d_in[7];
    const float* bs  = (const float*)d_in[8];
    const float* gc  = (const float*)d_in[9];
    const float* bc  = (const float*)d_in[10];
    const float* go  = (const float*)d_in[11];
    const float* bo  = (const float*)d_in[12];
    const float* W1  = (const float*)d_in[13];
    const float* b1  = (const float*)d_in[14];
    const float* W2  = (const float*)d_in[15];
    const float* b2  = (const float*)d_in[16];
    float* out = (float*)d_out;

    char* ws = (char*)d_ws;
    float*  x      = (float*)(ws + X_OFF);
    float*  agg    = (float*)(ws + AGG_OFF);
    double* stA    = (double*)(ws + STA_OFF);
    double* stB    = (double*)(ws + STB_OFF);
    float*  pooled = (float*)(ws + POOL_OFF);
    float*  cnt    = (float*)(ws + CNT_OFF);
    int*    deg    = (int*)(ws + DEG_OFF);
    int*    ecur   = (int*)(ws + ECUR_OFF);
    int*    perm   = (int*)(ws + PERM_OFF);
    int*    dst_s  = (int*)(ws + DSTS_OFF);
    int*    src_s  = (int*)(ws + SRCS_OFF);
    int*    bsum   = (int*)(ws + BSUM_OFF);
    int*    boff   = (int*)(ws + BOFF_OFF);
    float*  parts  = (float*)(ws + PART_OFF);
    float*  P      = (float*)(ws + P_OFF);

    // zero agg (layer 0), pool buffers, histogram
    (void)hipMemsetAsync(ws + AGG_OFF, 0, 25600000, stream);
    (void)hipMemsetAsync(ws + POOL_OFF, 0, 131072 + 2048, stream);
    (void)hipMemsetAsync(ws + DEG_OFF, 0, 400000, stream);

    // ---- counting sort of edges by dst (once per call) ----
    cg_hist<<<(N_EDGES + 255) / 256, 256, 0, stream>>>(ei, deg);
    cg_bsum<<<SCAN_BLOCKS, 256, 0, stream>>>(deg, bsum);
    cg_bscan<<<1, 512, 0, stream>>>(bsum, boff);
    cg_escan<<<SCAN_BLOCKS, 256, 0, stream>>>(deg, boff, ecur);
    cg_scatter<<<(N_EDGES + 255) / 256, 256, 0, stream>>>(ei, ecur, perm, dst_s, src_s);

    cg_embed<<<(N_NODES * HID + 255) / 256, 256, 0, stream>>>(z, emb, x);

    for (int l = 0; l < LAYERS; l++) {
        const float* Wfl = Wf + (size_t)l * 160 * HID;
        const float* Wsl = Ws + (size_t)l * 160 * HID;
        cg_nodeP4<<<(N_NODES + 63) / 64, 256, 0, stream>>>(x, Wfl, Wsl, P);
        cg_edge4<<<1024, 256, 0, stream>>>(P, ea, perm, dst_s, src_s,
                                           Wfl + 128 * HID, Wsl + 128 * HID,
                                           bf + l * HID, bs + l * HID, agg);
        cg_stats<<<NPB, 256, 0, stream>>>(agg, parts);
        cg_fin<<<1, 256, 0, stream>>>(parts, stA);
        cg_bn1res<<<NPB, 256, 0, stream>>>(agg, x, gc + l * HID, bc + l * HID, stA, parts);
        cg_fin<<<1, 256, 0, stream>>>(parts, stB);
        cg_bn2act<<<NPB, 256, 0, stream>>>(agg, x, go + l * HID, bo + l * HID, stB);
    }

    cg_pool<<<1024, 256, 0, stream>>>(x, bid, pooled, cnt);
    cg_mlp<<<N_GRAPHS, 64, 0, stream>>>(pooled, cnt, W1, b1, W2, b2, out);
}